// Round 1
// baseline (1269.745 us; speedup 1.0000x reference)
//
#include <hip/hip_runtime.h>
#include <hip/hip_fp16.h>
#include <cstdint>
#include <cstddef>

#define NPB_SHIFT 7                      // 128 dst-nodes per bucket
#define NPB (1 << NPB_SHIFT)
#define CHUNK 4096                       // edges per partition block
#define BCHUNK 8192                      // edges per bucket-count block
// nbuck = ceil(N/128) must be <= 1024 (N <= 131072) for the LDS arrays below.

typedef _Float16 half8_t __attribute__((ext_vector_type(8)));
typedef _Float16 half4_t __attribute__((ext_vector_type(4)));
typedef _Float16 half2_t __attribute__((ext_vector_type(2)));
typedef float floatx4 __attribute__((ext_vector_type(4)));

#define H2(u) __builtin_bit_cast(half2_t, (u))

// ---------------- graph preprocessing ----------------

// bucket histogram: LDS-aggregated, <=nbuck global atomics per block
__global__ __launch_bounds__(256) void k_bcount(const int* __restrict__ dst,
                                                int* __restrict__ btot, int E, int nbuck) {
  __shared__ int cnt[1024];
  int tid = threadIdx.x;
  for (int i = tid; i < 1024; i += 256) cnt[i] = 0;
  __syncthreads();
  int base = blockIdx.x * BCHUNK;
  int end = min(base + BCHUNK, E);
  for (int e = base + tid; e < end; e += 256) atomicAdd(&cnt[dst[e] >> NPB_SHIFT], 1);
  __syncthreads();
  for (int i = tid; i < nbuck; i += 256)
    if (cnt[i]) atomicAdd(&btot[i], cnt[i]);
}

// exclusive scan of bucket totals -> bucket bases (+ copy to bfill); 1024 threads
__global__ void k_bscan(const int* __restrict__ btot, int* __restrict__ bbase,
                        int* __restrict__ bfill, int nbuck, int E) {
  __shared__ int tmp[1024];
  int tid = threadIdx.x;
  int v = (tid < nbuck) ? btot[tid] : 0;
  tmp[tid] = v;
  __syncthreads();
  for (int off = 1; off < 1024; off <<= 1) {
    int t = (tid >= off) ? tmp[tid - off] : 0;
    __syncthreads();
    tmp[tid] += t;
    __syncthreads();
  }
  if (tid < nbuck) { int ex = tmp[tid] - v; bbase[tid] = ex; bfill[tid] = ex; }
  if (tid == 0) bbase[nbuck] = E;
}

// pass 1: LDS multisplit with in-LDS bucket sort; writes to tmp are
// LDS-order sequential -> coalesced runs per bucket segment.
// tmp[e] = (src << NPB_SHIFT) | dst_local  -- consumed directly by k_agg_lds.
__global__ __launch_bounds__(256) void k_partition(const int* __restrict__ src,
                                                   const int* __restrict__ dst,
                                                   int* __restrict__ bfill,
                                                   unsigned* __restrict__ tmp,
                                                   int E, int nbuck) {
  __shared__ int cnt[1024];
  __shared__ int lbase[1024];
  __shared__ int gdelta[1024];
  __shared__ int cur[1024];
  __shared__ int ps[256];
  __shared__ unsigned sval[CHUNK];
  __shared__ unsigned short sbid[CHUNK];
  int tid = threadIdx.x;
  int cbase = blockIdx.x * CHUNK;
  for (int i = tid; i < 1024; i += 256) cnt[i] = 0;
  __syncthreads();
  int s[16], d[16];
  bool valid[16];
#pragma unroll
  for (int u = 0; u < 16; ++u) {
    int e = cbase + u * 256 + tid;
    valid[u] = e < E;
    s[u] = valid[u] ? src[e] : 0;
    d[u] = valid[u] ? dst[e] : 0;
    if (valid[u]) atomicAdd(&cnt[d[u] >> NPB_SHIFT], 1);
  }
  __syncthreads();
  // block-local exclusive scan of cnt[1024] (4 entries per thread)
  int c0 = cnt[4 * tid], c1 = cnt[4 * tid + 1], c2 = cnt[4 * tid + 2], c3 = cnt[4 * tid + 3];
  int p = c0 + c1 + c2 + c3;
  ps[tid] = p;
  __syncthreads();
  for (int off = 1; off < 256; off <<= 1) {
    int t = (tid >= off) ? ps[tid - off] : 0;
    __syncthreads();
    ps[tid] += t;
    __syncthreads();
  }
  int ep = ps[tid] - p;                  // exclusive over quads
  lbase[4 * tid] = ep;
  lbase[4 * tid + 1] = ep + c0;
  lbase[4 * tid + 2] = ep + c0 + c1;
  lbase[4 * tid + 3] = ep + c0 + c1 + c2;
  __syncthreads();
  for (int i = tid; i < 1024; i += 256) {
    cur[i] = lbase[i];
    if (cnt[i]) gdelta[i] = atomicAdd(&bfill[i], cnt[i]) - lbase[i];
  }
  __syncthreads();
  // scatter into LDS in bucket-sorted order
#pragma unroll
  for (int u = 0; u < 16; ++u) {
    if (valid[u]) {
      int b = d[u] >> NPB_SHIFT;
      int r = atomicAdd(&cur[b], 1);
      sval[r] = ((unsigned)s[u] << NPB_SHIFT) | (unsigned)(d[u] & (NPB - 1));
      sbid[r] = (unsigned short)b;
    }
  }
  __syncthreads();
  // sequential LDS read -> coalesced global writes (runs per bucket)
  int nv = min(CHUNK, E - cbase);
  for (int i = tid; i < nv; i += 256) {
    unsigned v = sval[i];
    int b = sbid[i];
    tmp[gdelta[b] + i] = v;
  }
}

// per bucket: in-degree count -> dinv (replaces CSR build; no scatter needed)
__global__ __launch_bounds__(256) void k_dinv(const unsigned* __restrict__ tmp,
                                              const int* __restrict__ bbase,
                                              float* __restrict__ dinv, int N) {
  __shared__ int cnt[NPB];
  int b = blockIdx.x, tid = threadIdx.x;
  if (tid < NPB) cnt[tid] = 0;
  __syncthreads();
  int ebeg = bbase[b], eend = bbase[b + 1];
  for (int j = ebeg + tid; j < eend; j += 256) atomicAdd(&cnt[tmp[j] & (NPB - 1)], 1);
  __syncthreads();
  int node = (b << NPB_SHIFT) + tid;
  if (tid < NPB && node < N) dinv[node] = rsqrtf((float)(cnt[tid] + 1));
}

// ---------------- dense layers: MFMA 16x16x32 f16, output scaled by dinv ------
// Writes g[node] = dinv[node] * (x @ W)[node] as fp16, row stride OS.
template <int K, int COLS, int MT, int KC, int OS, typename XT>
__global__ __launch_bounds__(256) void k_gemm_mfma(const XT* __restrict__ x,
                                                   const float* __restrict__ W,
                                                   const float* __restrict__ dinv,
                                                   _Float16* __restrict__ out, int n) {
  int lane = threadIdx.x & 63;
  int quad = lane >> 4;
  int l15 = lane & 15;
  int gwave = (blockIdx.x * blockDim.x + threadIdx.x) >> 6;
  int nwave = (gridDim.x * blockDim.x) >> 6;
  int ntiles = (n + 15) >> 4;

  half8_t afrag[MT][KC];
#pragma unroll
  for (int m = 0; m < MT; ++m) {
    int colw = m * 16 + l15;
    if (colw > COLS - 1) colw = COLS - 1;
#pragma unroll
    for (int c = 0; c < KC; ++c) {
#pragma unroll
      for (int j = 0; j < 8; ++j) {
        int kk = c * 32 + quad * 8 + j;
        afrag[m][c][j] = (_Float16)W[kk * COLS + colw];
      }
    }
  }

  for (int tile = gwave; tile < ntiles; tile += nwave) {
    int node0 = tile << 4;
    int nodeB = node0 + l15;
    int nodeC = nodeB < n ? nodeB : n - 1;
    const XT* xr = x + (size_t)nodeC * K;
    float dv = dinv[nodeC];
    half8_t bfrag[KC];
#pragma unroll
    for (int c = 0; c < KC; ++c) {
      if constexpr (sizeof(XT) == 4) {
        float4 lo = *(const float4*)(xr + c * 32 + quad * 8);
        float4 hi = *(const float4*)(xr + c * 32 + quad * 8 + 4);
        bfrag[c][0] = (_Float16)lo.x; bfrag[c][1] = (_Float16)lo.y;
        bfrag[c][2] = (_Float16)lo.z; bfrag[c][3] = (_Float16)lo.w;
        bfrag[c][4] = (_Float16)hi.x; bfrag[c][5] = (_Float16)hi.y;
        bfrag[c][6] = (_Float16)hi.z; bfrag[c][7] = (_Float16)hi.w;
      } else {
        bfrag[c] = *(const half8_t*)(xr + c * 32 + quad * 8);
      }
    }
    floatx4 acc[MT];
#pragma unroll
    for (int m = 0; m < MT; ++m) acc[m] = (floatx4){0.f, 0.f, 0.f, 0.f};
#pragma unroll
    for (int c = 0; c < KC; ++c)
#pragma unroll
      for (int m = 0; m < MT; ++m)
        acc[m] = __builtin_amdgcn_mfma_f32_16x16x32_f16(afrag[m][c], bfrag[c], acc[m], 0, 0, 0);

    if (nodeB < n) {
#pragma unroll
      for (int m = 0; m < MT; ++m) {
        int colBase = m * 16 + quad * 4;
        if (colBase < COLS) {
          half4_t hv = {(_Float16)(acc[m][0] * dv), (_Float16)(acc[m][1] * dv),
                        (_Float16)(acc[m][2] * dv), (_Float16)(acc[m][3] * dv)};
          *(half4_t*)(out + (size_t)nodeB * OS + colBase) = hv;
        }
      }
    }
  }
}

// ---------------- aggregation: edge-parallel push into LDS fp32 tile ----------
// One block per dst bucket (NPB=128 nodes). Edges come from tmp[] already
// bucket-sorted and packed (src<<7)|dloc. 32 groups x 8 lanes: group g takes
// edge stream positions (coalesced index reads, independent gathers -> deep
// MLP), lane t gathers uint4 = 8 fp16 feats, fp32-atomics into LDS.
// Odd STRIDE makes bank = (dloc*odd + 8t + j) % 32 -> ~2-way (free).
// Epilogue: out = dinv*(acc + g[self]) + bias (+relu), coalesced store.

__device__ inline void addrow8(float* a, uint4 r) {
  half2_t h0 = H2(r.x), h1 = H2(r.y), h2 = H2(r.z), h3 = H2(r.w);
  atomicAdd(a + 0, (float)h0[0]); atomicAdd(a + 1, (float)h0[1]);
  atomicAdd(a + 2, (float)h1[0]); atomicAdd(a + 3, (float)h1[1]);
  atomicAdd(a + 4, (float)h2[0]); atomicAdd(a + 5, (float)h2[1]);
  atomicAdd(a + 6, (float)h3[0]); atomicAdd(a + 7, (float)h3[1]);
}

template <int F, bool RELU, bool OUT_HALF>
__global__ __launch_bounds__(256) void k_agg_lds(const unsigned* __restrict__ tmp,
                                                 const int* __restrict__ bbase,
                                                 const uint4* __restrict__ g8,
                                                 const float* __restrict__ dinv,
                                                 const float* __restrict__ bias,
                                                 void* __restrict__ outp, int N) {
  constexpr int F8 = F / 8;              // uint4s per feature row (8 or 5)
  constexpr int STRIDE = F + 1;          // 65 / 41 -- odd, bank-spreading
  __shared__ float accs[NPB * STRIDE];   // 33.3 KB (F=64) / 21 KB (F=40)
  int tid = threadIdx.x;
  int gid = tid >> 3;                    // edge group 0..31
  int t = tid & 7;                       // feature octet
  int b = blockIdx.x;
  bool tv = t < F8;

  for (int i = tid; i < NPB * STRIDE; i += 256) accs[i] = 0.f;
  __syncthreads();

  int ebeg = bbase[b], eend = bbase[b + 1];
  int e = ebeg + gid;
  for (; e + 32 < eend; e += 64) {       // 2 edges per group in flight
    unsigned v0 = tmp[e];
    unsigned v1 = tmp[e + 32];
    uint4 r0 = tv ? g8[(size_t)(v0 >> NPB_SHIFT) * F8 + t] : make_uint4(0, 0, 0, 0);
    uint4 r1 = tv ? g8[(size_t)(v1 >> NPB_SHIFT) * F8 + t] : make_uint4(0, 0, 0, 0);
    if (tv) {
      addrow8(accs + (int)(v0 & (NPB - 1)) * STRIDE + t * 8, r0);
      addrow8(accs + (int)(v1 & (NPB - 1)) * STRIDE + t * 8, r1);
    }
  }
  if (e < eend) {
    unsigned v0 = tmp[e];
    if (tv) {
      uint4 r0 = g8[(size_t)(v0 >> NPB_SHIFT) * F8 + t];
      addrow8(accs + (int)(v0 & (NPB - 1)) * STRIDE + t * 8, r0);
    }
  }
  __syncthreads();

  // epilogue: each group handles 4 nodes
  for (int nl = gid; nl < NPB; nl += 32) {
    int node = (b << NPB_SHIFT) + nl;
    if (node < N && tv) {
      float di = dinv[node];
      uint4 sv = g8[(size_t)node * F8 + t];     // self-loop term g[node]
      half2_t h0 = H2(sv.x), h1 = H2(sv.y), h2 = H2(sv.z), h3 = H2(sv.w);
      float sf[8] = {(float)h0[0], (float)h0[1], (float)h1[0], (float)h1[1],
                     (float)h2[0], (float)h2[1], (float)h3[0], (float)h3[1]};
      const float* a = accs + nl * STRIDE + t * 8;
      const float* bb = bias + t * 8;
      float o[8];
#pragma unroll
      for (int j = 0; j < 8; ++j) {
        o[j] = fmaf(a[j] + sf[j], di, bb[j]);
        if (RELU) o[j] = fmaxf(o[j], 0.f);
      }
      if (OUT_HALF) {
        _Float16* op = (_Float16*)outp + (size_t)node * F + t * 8;
        uint4 w;
        half2_t p0 = {(_Float16)o[0], (_Float16)o[1]};
        half2_t p1 = {(_Float16)o[2], (_Float16)o[3]};
        half2_t p2 = {(_Float16)o[4], (_Float16)o[5]};
        half2_t p3 = {(_Float16)o[6], (_Float16)o[7]};
        w.x = __builtin_bit_cast(unsigned, p0);
        w.y = __builtin_bit_cast(unsigned, p1);
        w.z = __builtin_bit_cast(unsigned, p2);
        w.w = __builtin_bit_cast(unsigned, p3);
        *(uint4*)op = w;
      } else {
        float* op = (float*)outp + (size_t)node * F + t * 8;
        *(float4*)op = make_float4(o[0], o[1], o[2], o[3]);
        *(float4*)(op + 4) = make_float4(o[4], o[5], o[6], o[7]);
      }
    }
  }
}

// ---------------- launch ----------------

extern "C" void kernel_launch(void* const* d_in, const int* in_sizes, int n_in,
                              void* d_out, int out_size, void* d_ws, size_t ws_size,
                              hipStream_t stream) {
  const float* x  = (const float*)d_in[0];
  const int*   ei = (const int*)d_in[1];
  const float* W1 = (const float*)d_in[2];
  const float* b1 = (const float*)d_in[3];
  const float* W2 = (const float*)d_in[4];
  const float* b2 = (const float*)d_in[5];
  float* out = (float*)d_out;

  const int F_IN = 128, HID = 64, C = 40;
  int N = in_sizes[0] / F_IN;
  int E = in_sizes[1] / 2;
  const int* src = ei;
  const int* dst = ei + E;
  int nbuck = (N + NPB - 1) >> NPB_SHIFT;   // 782 for N=100000

  char* w = (char*)d_ws;
  size_t o = 0;
  auto alloc = [&](size_t bytes) -> void* {
    void* p = w + o;
    o = (o + bytes + 255) & ~(size_t)255;
    return p;
  };
  float*    dinv   = (float*)alloc((size_t)N * 4);
  int*      btot   = (int*)alloc(1024 * 4);
  int*      bbase  = (int*)alloc(1025 * 4);
  int*      bfill  = (int*)alloc(1024 * 4);
  unsigned* tmp    = (unsigned*)alloc((size_t)E * 4);
  _Float16* g1     = (_Float16*)alloc((size_t)N * HID * 2);   // dinv*(xW1), stride 64
  _Float16* h1     = (_Float16*)alloc((size_t)N * HID * 2);   // relu layer-1 out, fp16
  _Float16* g2     = (_Float16*)alloc((size_t)N * C * 2);     // dinv*(h1W2), stride 40

  dim3 b256(256);

  // bucket totals -> bases
  hipMemsetAsync(btot, 0, 1024 * 4, stream);
  k_bcount<<<dim3((E + BCHUNK - 1) / BCHUNK), b256, 0, stream>>>(dst, btot, E, nbuck);
  k_bscan<<<dim3(1), dim3(1024), 0, stream>>>(btot, bbase, bfill, nbuck, E);

  // partition into bucket-sorted packed (src|dloc) edges; per-bucket degrees
  k_partition<<<dim3((E + CHUNK - 1) / CHUNK), b256, 0, stream>>>(src, dst, bfill, tmp, E, nbuck);
  k_dinv<<<dim3(nbuck), b256, 0, stream>>>(tmp, bbase, dinv, N);

  // layer 1: g1 = dinv * (x @ W1);  h1 = relu(dinv*(g1[self]+sum g1[src]) + b1)
  k_gemm_mfma<128, 64, 4, 4, 64, float><<<dim3(256), b256, 0, stream>>>(x, W1, dinv, g1, N);
  k_agg_lds<64, true, true><<<dim3(nbuck), b256, 0, stream>>>(
      tmp, bbase, (const uint4*)g1, dinv, b1, h1, N);

  // layer 2: g2 = dinv * (h1 @ W2); out = dinv*(g2[self]+sum g2[src]) + b2
  k_gemm_mfma<64, 40, 3, 2, 40, _Float16><<<dim3(256), b256, 0, stream>>>(h1, W2, dinv, g2, N);
  k_agg_lds<40, false, false><<<dim3(nbuck), b256, 0, stream>>>(
      tmp, bbase, (const uint4*)g2, dinv, b2, out, N);
}

// Round 2
// 264.051 us; speedup vs baseline: 4.8087x; 4.8087x over previous
//
#include <hip/hip_runtime.h>
#include <hip/hip_fp16.h>
#include <cstdint>
#include <cstddef>

#define NPB_SHIFT 8                      // 256 dst-nodes per bucket
#define NPB (1 << NPB_SHIFT)
#define CHUNK 4096                       // edges per partition block
#define BCHUNK 8192                      // edges per bucket-count block
// nbuck = ceil(N/256) must be <= 512 (N <= 131072) for the LDS arrays below.

typedef _Float16 half8_t __attribute__((ext_vector_type(8)));
typedef _Float16 half4_t __attribute__((ext_vector_type(4)));
typedef _Float16 half2_t __attribute__((ext_vector_type(2)));
typedef float floatx4 __attribute__((ext_vector_type(4)));

#define H2(u) __builtin_bit_cast(half2_t, (u))

// ---------------- graph preprocessing ----------------

// bucket histogram: LDS-aggregated, <=nbuck global atomics per block
__global__ __launch_bounds__(256) void k_bcount(const int* __restrict__ dst,
                                                int* __restrict__ btot, int E, int nbuck) {
  __shared__ int cnt[512];
  int tid = threadIdx.x;
  for (int i = tid; i < nbuck; i += 256) cnt[i] = 0;
  __syncthreads();
  int base = blockIdx.x * BCHUNK;
  int end = min(base + BCHUNK, E);
  for (int e = base + tid; e < end; e += 256) atomicAdd(&cnt[dst[e] >> NPB_SHIFT], 1);
  __syncthreads();
  for (int i = tid; i < nbuck; i += 256)
    if (cnt[i]) atomicAdd(&btot[i], cnt[i]);
}

// exclusive scan of bucket totals -> bucket bases (+ copy to bfill)
__global__ void k_bscan(const int* __restrict__ btot, int* __restrict__ bbase,
                        int* __restrict__ bfill, int nbuck, int E) {
  __shared__ int tmp[512];
  int tid = threadIdx.x;
  int v = (tid < nbuck) ? btot[tid] : 0;
  tmp[tid] = v;
  __syncthreads();
  for (int off = 1; off < 512; off <<= 1) {
    int t = (tid >= off) ? tmp[tid - off] : 0;
    __syncthreads();
    tmp[tid] += t;
    __syncthreads();
  }
  if (tid < nbuck) { int ex = tmp[tid] - v; bbase[tid] = ex; bfill[tid] = ex; }
  if (tid == 0) bbase[nbuck] = E;
}

// pass 1: LDS multisplit with in-LDS bucket sort; writes to tmp are
// LDS-order sequential -> coalesced runs per bucket segment.
__global__ __launch_bounds__(256) void k_partition(const int* __restrict__ src,
                                                   const int* __restrict__ dst,
                                                   int* __restrict__ bfill,
                                                   unsigned* __restrict__ tmp,
                                                   int E, int nbuck) {
  __shared__ int cnt[512];
  __shared__ int lbase[512];
  __shared__ int gdelta[512];
  __shared__ int cur[512];
  __shared__ int ps[256];
  __shared__ unsigned sval[CHUNK];
  __shared__ unsigned short sbid[CHUNK];
  int tid = threadIdx.x;
  int cbase = blockIdx.x * CHUNK;
  for (int i = tid; i < 512; i += 256) cnt[i] = 0;
  __syncthreads();
  int s[16], d[16];
  bool valid[16];
#pragma unroll
  for (int u = 0; u < 16; ++u) {
    int e = cbase + u * 256 + tid;
    valid[u] = e < E;
    s[u] = valid[u] ? src[e] : 0;
    d[u] = valid[u] ? dst[e] : 0;
    if (valid[u]) atomicAdd(&cnt[d[u] >> NPB_SHIFT], 1);
  }
  __syncthreads();
  // block-local exclusive scan of cnt[512] (2 entries per thread)
  int c0 = cnt[2 * tid], c1 = cnt[2 * tid + 1];
  int p = c0 + c1;
  ps[tid] = p;
  __syncthreads();
  for (int off = 1; off < 256; off <<= 1) {
    int t = (tid >= off) ? ps[tid - off] : 0;
    __syncthreads();
    ps[tid] += t;
    __syncthreads();
  }
  int ep = ps[tid] - p;                  // exclusive over pairs
  lbase[2 * tid] = ep;
  lbase[2 * tid + 1] = ep + c0;
  __syncthreads();
  for (int i = tid; i < 512; i += 256) {
    cur[i] = lbase[i];
    if (cnt[i]) gdelta[i] = atomicAdd(&bfill[i], cnt[i]) - lbase[i];
  }
  __syncthreads();
  // scatter into LDS in bucket-sorted order
#pragma unroll
  for (int u = 0; u < 16; ++u) {
    if (valid[u]) {
      int b = d[u] >> NPB_SHIFT;
      int r = atomicAdd(&cur[b], 1);
      sval[r] = ((unsigned)s[u] << NPB_SHIFT) | (unsigned)(d[u] & (NPB - 1));
      sbid[r] = (unsigned short)b;
    }
  }
  __syncthreads();
  // sequential LDS read -> coalesced global writes (runs per bucket)
  int nv = min(CHUNK, E - cbase);
  for (int i = tid; i < nv; i += 256) {
    unsigned v = sval[i];
    int b = sbid[i];
    tmp[gdelta[b] + i] = v;
  }
}

// per bucket (merged): LDS degree count -> dinv + offsets, then src-only CSR
// scatter. No remote-node data needed since norms are folded into the GEMMs.
__global__ __launch_bounds__(256) void k_csr_build(const unsigned* __restrict__ tmp,
                                                   const int* __restrict__ bbase,
                                                   float* __restrict__ dinv,
                                                   int* __restrict__ offset,
                                                   int* __restrict__ ssrc,
                                                   int N, int E, int nbuck) {
  __shared__ int cnt[NPB];
  __shared__ int scan[NPB];
  __shared__ int fillL[NPB];
  int b = blockIdx.x, tid = threadIdx.x;
  int nbase = b << NPB_SHIFT;
  int nloc = min(NPB, N - nbase);
  cnt[tid] = 0;
  __syncthreads();
  int ebeg = bbase[b], eend = bbase[b + 1];
  for (int j = ebeg + tid; j < eend; j += 256) atomicAdd(&cnt[tmp[j] & (NPB - 1)], 1);
  __syncthreads();
  int v = cnt[tid];
  scan[tid] = v;
  __syncthreads();
  for (int off = 1; off < NPB; off <<= 1) {
    int t = (tid >= off) ? scan[tid - off] : 0;
    __syncthreads();
    scan[tid] += t;
    __syncthreads();
  }
  int myoff = ebeg + scan[tid] - v;   // exclusive
  fillL[tid] = myoff;
  if (tid < nloc) {
    offset[nbase + tid] = myoff;
    dinv[nbase + tid] = rsqrtf((float)(v + 1));   // +1 self-loop
  }
  if (b == nbuck - 1 && tid == 0) offset[N] = E;
  __syncthreads();
  // scatter src indices into exact CSR slots (LDS fill counters, L2-local writes)
  int j = ebeg + tid;
  for (; j + 3 * 256 < eend; j += 4 * 256) {
    unsigned p[4];
#pragma unroll
    for (int u = 0; u < 4; ++u) p[u] = tmp[j + u * 256];
#pragma unroll
    for (int u = 0; u < 4; ++u) {
      int pos = atomicAdd(&fillL[p[u] & (NPB - 1)], 1);
      ssrc[pos] = (int)(p[u] >> NPB_SHIFT);
    }
  }
  for (; j < eend; j += 256) {
    unsigned p = tmp[j];
    int pos = atomicAdd(&fillL[p & (NPB - 1)], 1);
    ssrc[pos] = (int)(p >> NPB_SHIFT);
  }
}

// ---------------- dense layers: MFMA 16x16x32 f16, output scaled by dinv ------
// Writes g[node] = dinv[node] * (x @ W)[node] as fp16, row stride OS.
template <int K, int COLS, int MT, int KC, int OS, typename XT>
__global__ __launch_bounds__(256) void k_gemm_mfma(const XT* __restrict__ x,
                                                   const float* __restrict__ W,
                                                   const float* __restrict__ dinv,
                                                   _Float16* __restrict__ out, int n) {
  int lane = threadIdx.x & 63;
  int quad = lane >> 4;
  int l15 = lane & 15;
  int gwave = (blockIdx.x * blockDim.x + threadIdx.x) >> 6;
  int nwave = (gridDim.x * blockDim.x) >> 6;
  int ntiles = (n + 15) >> 4;

  half8_t afrag[MT][KC];
#pragma unroll
  for (int m = 0; m < MT; ++m) {
    int colw = m * 16 + l15;
    if (colw > COLS - 1) colw = COLS - 1;
#pragma unroll
    for (int c = 0; c < KC; ++c) {
#pragma unroll
      for (int j = 0; j < 8; ++j) {
        int kk = c * 32 + quad * 8 + j;
        afrag[m][c][j] = (_Float16)W[kk * COLS + colw];
      }
    }
  }

  for (int tile = gwave; tile < ntiles; tile += nwave) {
    int node0 = tile << 4;
    int nodeB = node0 + l15;
    int nodeC = nodeB < n ? nodeB : n - 1;
    const XT* xr = x + (size_t)nodeC * K;
    float dv = dinv[nodeC];
    half8_t bfrag[KC];
#pragma unroll
    for (int c = 0; c < KC; ++c) {
      if constexpr (sizeof(XT) == 4) {
        float4 lo = *(const float4*)(xr + c * 32 + quad * 8);
        float4 hi = *(const float4*)(xr + c * 32 + quad * 8 + 4);
        bfrag[c][0] = (_Float16)lo.x; bfrag[c][1] = (_Float16)lo.y;
        bfrag[c][2] = (_Float16)lo.z; bfrag[c][3] = (_Float16)lo.w;
        bfrag[c][4] = (_Float16)hi.x; bfrag[c][5] = (_Float16)hi.y;
        bfrag[c][6] = (_Float16)hi.z; bfrag[c][7] = (_Float16)hi.w;
      } else {
        bfrag[c] = *(const half8_t*)(xr + c * 32 + quad * 8);
      }
    }
    floatx4 acc[MT];
#pragma unroll
    for (int m = 0; m < MT; ++m) acc[m] = (floatx4){0.f, 0.f, 0.f, 0.f};
#pragma unroll
    for (int c = 0; c < KC; ++c)
#pragma unroll
      for (int m = 0; m < MT; ++m)
        acc[m] = __builtin_amdgcn_mfma_f32_16x16x32_f16(afrag[m][c], bfrag[c], acc[m], 0, 0, 0);

    if (nodeB < n) {
#pragma unroll
      for (int m = 0; m < MT; ++m) {
        int colBase = m * 16 + quad * 4;
        if (colBase < COLS) {
          half4_t hv = {(_Float16)(acc[m][0] * dv), (_Float16)(acc[m][1] * dv),
                        (_Float16)(acc[m][2] * dv), (_Float16)(acc[m][3] * dv)};
          *(half4_t*)(out + (size_t)nodeB * OS + colBase) = hv;
        }
      }
    }
  }
}

// ---------------- aggregation: 4 nodes per wave, 8 gathers in flight ----------
// Wave = 8 groups x 8 lanes. Each wave owns 4 consecutive nodes; per
// super-iteration it issues 8 independent ssrc loads then 8 independent uint4
// gathers (4 nodes x 2 segments), then packed-fp16 accumulates. This turns the
// round-0 single dependent chain (2 gathers in flight) into an 8-deep MLP.
// out = dinv*(g[self]+sum g[src]) + bias, optional relu, fp16 or fp32 out.

__device__ __forceinline__ void addacc(half2_t* acc, uint4 r) {
  acc[0] += H2(r.x); acc[1] += H2(r.y); acc[2] += H2(r.z); acc[3] += H2(r.w);
}

template <int F, int S8, bool RELU, bool OUT_HALF>
__global__ __launch_bounds__(256) void k_agg_v4(const uint4* __restrict__ g8,
                                                const int* __restrict__ offset,
                                                const int* __restrict__ ssrc,
                                                const float* __restrict__ dinv,
                                                const float* __restrict__ bias,
                                                void* __restrict__ outp, int n) {
  constexpr int F8 = F / 8;            // used octets per row (8 or 5)
  int lane = threadIdx.x & 63;
  int g = lane >> 3;                   // edge group 0..7
  int t = lane & 7;                    // feature octet
  int wave = (blockIdx.x * blockDim.x + threadIdx.x) >> 6;
  int nb = wave * 4;                   // first node of this wave
  if (nb >= n) return;
  bool tv = t < F8;

  // self-loop gathers first (independent, start early)
  uint4 sv[4];
#pragma unroll
  for (int w = 0; w < 4; ++w) {
    int node = nb + w;
    int nc = node < n ? node : n - 1;
    sv[w] = (tv && g == 0 && node < n) ? g8[(size_t)nc * S8 + t]
                                       : make_uint4(0, 0, 0, 0);
  }

  int jj[4], ee[4];
  float di[4];
#pragma unroll
  for (int w = 0; w < 4; ++w) {
    int node = nb + w;
    bool nv = node < n;
    int nc = nv ? node : n - 1;
    int b0 = offset[nc];
    int b1 = offset[nc + 1];
    jj[w] = b0;
    ee[w] = nv ? b1 : b0;
    di[w] = dinv[nc];
  }

  half2_t acc[4][4];
#pragma unroll
  for (int w = 0; w < 4; ++w) {
#pragma unroll
    for (int k = 0; k < 4; ++k) acc[w][k] = H2(0u);
    addacc(acc[w], sv[w]);
  }

  // main loop: up to 16 edges per node per iteration, 8 gathers in flight
  for (;;) {
    bool a0[4], a1[4];
    bool any = false;
#pragma unroll
    for (int w = 0; w < 4; ++w) {
      a0[w] = jj[w] + 8 <= ee[w];
      a1[w] = jj[w] + 16 <= ee[w];
      any = any || a0[w];
    }
    if (!any) break;
    int s0[4], s1[4];
#pragma unroll
    for (int w = 0; w < 4; ++w) {
      s0[w] = a0[w] ? ssrc[jj[w] + g] : 0;
      s1[w] = a1[w] ? ssrc[jj[w] + 8 + g] : 0;
    }
    uint4 r0[4], r1[4];
#pragma unroll
    for (int w = 0; w < 4; ++w) {
      r0[w] = (a0[w] && tv) ? g8[(size_t)s0[w] * S8 + t] : make_uint4(0, 0, 0, 0);
      r1[w] = (a1[w] && tv) ? g8[(size_t)s1[w] * S8 + t] : make_uint4(0, 0, 0, 0);
    }
#pragma unroll
    for (int w = 0; w < 4; ++w) {
      addacc(acc[w], r0[w]);
      addacc(acc[w], r1[w]);
      jj[w] += a1[w] ? 16 : (a0[w] ? 8 : 0);
    }
  }

  // masked tails (0..7 remaining edges per node), 4 gathers in flight
  {
    int rem[4];
    uint4 rv[4];
#pragma unroll
    for (int w = 0; w < 4; ++w) {
      rem[w] = ee[w] - jj[w];
      int gi = (g < rem[w]) ? g : (rem[w] - 1);
      int sW = rem[w] > 0 ? ssrc[jj[w] + gi] : 0;
      rv[w] = (tv && g < rem[w]) ? g8[(size_t)sW * S8 + t] : make_uint4(0, 0, 0, 0);
    }
#pragma unroll
    for (int w = 0; w < 4; ++w) addacc(acc[w], rv[w]);
  }

  // reduce across the 8 groups (packed shuffles) and write out
#pragma unroll
  for (int w = 0; w < 4; ++w) {
#pragma unroll
    for (int k = 0; k < 4; ++k) {
      int u = __builtin_bit_cast(int, acc[w][k]);
      acc[w][k] += H2((unsigned)__shfl_xor(u, 8));
      u = __builtin_bit_cast(int, acc[w][k]);
      acc[w][k] += H2((unsigned)__shfl_xor(u, 16));
      u = __builtin_bit_cast(int, acc[w][k]);
      acc[w][k] += H2((unsigned)__shfl_xor(u, 32));
    }
    int node = nb + w;
    if (node < n && lane < F8) {
      float f[8];
#pragma unroll
      for (int k = 0; k < 4; ++k) {
        f[2 * k] = (float)acc[w][k][0];
        f[2 * k + 1] = (float)acc[w][k][1];
      }
      const float* bb = bias + lane * 8;
      float o[8];
#pragma unroll
      for (int j = 0; j < 8; ++j) {
        o[j] = fmaf(f[j], di[w], bb[j]);
        if (RELU) o[j] = fmaxf(o[j], 0.f);
      }
      if (OUT_HALF) {
        _Float16* op = (_Float16*)outp + (size_t)node * F + lane * 8;
        half2_t p0 = {(_Float16)o[0], (_Float16)o[1]};
        half2_t p1 = {(_Float16)o[2], (_Float16)o[3]};
        half2_t p2 = {(_Float16)o[4], (_Float16)o[5]};
        half2_t p3 = {(_Float16)o[6], (_Float16)o[7]};
        uint4 wv;
        wv.x = __builtin_bit_cast(unsigned, p0);
        wv.y = __builtin_bit_cast(unsigned, p1);
        wv.z = __builtin_bit_cast(unsigned, p2);
        wv.w = __builtin_bit_cast(unsigned, p3);
        *(uint4*)op = wv;
      } else {
        float* op = (float*)outp + (size_t)node * F + lane * 8;
        *(float4*)op = make_float4(o[0], o[1], o[2], o[3]);
        *(float4*)(op + 4) = make_float4(o[4], o[5], o[6], o[7]);
      }
    }
  }
}

// ---------------- launch ----------------

extern "C" void kernel_launch(void* const* d_in, const int* in_sizes, int n_in,
                              void* d_out, int out_size, void* d_ws, size_t ws_size,
                              hipStream_t stream) {
  const float* x  = (const float*)d_in[0];
  const int*   ei = (const int*)d_in[1];
  const float* W1 = (const float*)d_in[2];
  const float* b1 = (const float*)d_in[3];
  const float* W2 = (const float*)d_in[4];
  const float* b2 = (const float*)d_in[5];
  float* out = (float*)d_out;

  const int F_IN = 128, HID = 64, C = 40;
  int N = in_sizes[0] / F_IN;
  int E = in_sizes[1] / 2;
  const int* src = ei;
  const int* dst = ei + E;
  int nbuck = (N + NPB - 1) >> NPB_SHIFT;   // 391 for N=100000

  char* w = (char*)d_ws;
  size_t o = 0;
  auto alloc = [&](size_t bytes) -> void* {
    void* p = w + o;
    o = (o + bytes + 255) & ~(size_t)255;
    return p;
  };
  float*    dinv   = (float*)alloc((size_t)N * 4);
  int*      offset = (int*)alloc((size_t)(N + 1) * 4);
  int*      btot   = (int*)alloc(512 * 4);
  int*      bbase  = (int*)alloc(513 * 4);
  int*      bfill  = (int*)alloc(512 * 4);
  unsigned* tmp    = (unsigned*)alloc((size_t)E * 4);
  int*      ssrc   = (int*)alloc((size_t)E * 4);
  _Float16* g1     = (_Float16*)alloc((size_t)N * HID * 2);   // dinv*(xW1), stride 64
  _Float16* h1     = (_Float16*)alloc((size_t)N * HID * 2);   // relu layer-1 out, fp16
  _Float16* g2     = (_Float16*)alloc((size_t)N * C * 2);     // dinv*(h1W2), stride 40

  dim3 b256(256);

  // bucket totals -> bases
  hipMemsetAsync(btot, 0, 512 * 4, stream);
  k_bcount<<<dim3((E + BCHUNK - 1) / BCHUNK), b256, 0, stream>>>(dst, btot, E, nbuck);
  k_bscan<<<dim3(1), dim3(512), 0, stream>>>(btot, bbase, bfill, nbuck, E);

  // partition + merged per-bucket CSR build (no global per-node atomics)
  k_partition<<<dim3((E + CHUNK - 1) / CHUNK), b256, 0, stream>>>(src, dst, bfill, tmp, E, nbuck);
  k_csr_build<<<dim3(nbuck), b256, 0, stream>>>(tmp, bbase, dinv, offset, ssrc, N, E, nbuck);

  // layer 1: g1 = dinv * (x @ W1);  h1 = relu(dinv*(g1[self]+sum g1[src]) + b1)
  k_gemm_mfma<128, 64, 4, 4, 64, float><<<dim3(256), b256, 0, stream>>>(x, W1, dinv, g1, N);
  k_agg_v4<64, 8, true, true><<<dim3((N + 15) / 16), b256, 0, stream>>>(
      (const uint4*)g1, offset, ssrc, dinv, b1, h1, N);

  // layer 2: g2 = dinv * (h1 @ W2); out = dinv*(g2[self]+sum g2[src]) + b2
  k_gemm_mfma<64, 40, 3, 2, 40, _Float16><<<dim3(256), b256, 0, stream>>>(h1, W2, dinv, g2, N);
  k_agg_v4<40, 5, false, false><<<dim3((N + 15) / 16), b256, 0, stream>>>(
      (const uint4*)g2, offset, ssrc, dinv, b2, out, N);
}

// Round 4
// 250.993 us; speedup vs baseline: 5.0589x; 1.0520x over previous
//
#include <hip/hip_runtime.h>
#include <hip/hip_fp16.h>
#include <cstdint>
#include <cstddef>

#define NPB_SHIFT 8                      // 256 dst-nodes per bucket
#define NPB (1 << NPB_SHIFT)
#define CHUNK 4096                       // edges per partition block
#define BCAP 6144                        // slots per bucket slab (lambda=4096, +32 sigma)
// nbuck = ceil(N/256) must be <= 512 (N <= 131072) for the LDS arrays below.

typedef _Float16 half8_t __attribute__((ext_vector_type(8)));
typedef _Float16 half4_t __attribute__((ext_vector_type(4)));
typedef _Float16 half2_t __attribute__((ext_vector_type(2)));
typedef float floatx4 __attribute__((ext_vector_type(4)));

#define H2(u) __builtin_bit_cast(half2_t, (u))

// ---------------- graph preprocessing ----------------

// pass 1: LDS multisplit with in-LDS bucket sort; each bucket owns a fixed
// slab tmp[b*BCAP .. b*BCAP+count). bfill[b] is the bucket's fill cursor
// (starts at 0; no pre-scan needed). Writes are LDS-order sequential ->
// coalesced runs per bucket segment.
__global__ __launch_bounds__(256) void k_partition(const int* __restrict__ src,
                                                   const int* __restrict__ dst,
                                                   int* __restrict__ bfill,
                                                   unsigned* __restrict__ tmp,
                                                   int E, int nbuck) {
  __shared__ int cnt[512];
  __shared__ int lbase[512];
  __shared__ int gdelta[512];
  __shared__ int cur[512];
  __shared__ int ps[256];
  __shared__ unsigned sval[CHUNK];
  __shared__ unsigned short sbid[CHUNK];
  int tid = threadIdx.x;
  int cbase = blockIdx.x * CHUNK;
  for (int i = tid; i < 512; i += 256) cnt[i] = 0;
  __syncthreads();
  int s[16], d[16];
  bool valid[16];
#pragma unroll
  for (int u = 0; u < 16; ++u) {
    int e = cbase + u * 256 + tid;
    valid[u] = e < E;
    s[u] = valid[u] ? src[e] : 0;
    d[u] = valid[u] ? dst[e] : 0;
    if (valid[u]) atomicAdd(&cnt[d[u] >> NPB_SHIFT], 1);
  }
  __syncthreads();
  // block-local exclusive scan of cnt[512] (2 entries per thread)
  int c0 = cnt[2 * tid], c1 = cnt[2 * tid + 1];
  int p = c0 + c1;
  ps[tid] = p;
  __syncthreads();
  for (int off = 1; off < 256; off <<= 1) {
    int t = (tid >= off) ? ps[tid - off] : 0;
    __syncthreads();
    ps[tid] += t;
    __syncthreads();
  }
  int ep = ps[tid] - p;                  // exclusive over pairs
  lbase[2 * tid] = ep;
  lbase[2 * tid + 1] = ep + c0;
  __syncthreads();
  for (int i = tid; i < 512; i += 256) {
    cur[i] = lbase[i];
    if (cnt[i]) gdelta[i] = atomicAdd(&bfill[i], cnt[i]) - lbase[i];
  }
  __syncthreads();
  // scatter into LDS in bucket-sorted order
#pragma unroll
  for (int u = 0; u < 16; ++u) {
    if (valid[u]) {
      int b = d[u] >> NPB_SHIFT;
      int r = atomicAdd(&cur[b], 1);
      sval[r] = ((unsigned)s[u] << NPB_SHIFT) | (unsigned)(d[u] & (NPB - 1));
      sbid[r] = (unsigned short)b;
    }
  }
  __syncthreads();
  // sequential LDS read -> coalesced global writes (runs per bucket slab)
  int nv = min(CHUNK, E - cbase);
  for (int i = tid; i < nv; i += 256) {
    unsigned v = sval[i];
    int b = sbid[i];
    tmp[(size_t)b * BCAP + (gdelta[b] + i)] = v;
  }
}

// per bucket: scan all bucket counts in-LDS to get this bucket's DENSE base
// (fixes the slab-gap bug: offset[] must be gap-free so that offset[node+1]
// is always the true end, including at bucket boundaries). Then LDS degree
// count -> dinv + dense offsets, then src-only CSR scatter into dense ssrc.
__global__ __launch_bounds__(256) void k_csr_build(const unsigned* __restrict__ tmp,
                                                   const int* __restrict__ bfill,
                                                   float* __restrict__ dinv,
                                                   int* __restrict__ offset,
                                                   int* __restrict__ ssrc,
                                                   int N, int E, int nbuck) {
  __shared__ int cnt[NPB];
  __shared__ int scan[NPB];
  __shared__ int fillL[NPB];
  __shared__ int bs[512];
  __shared__ int ps[256];
  int b = blockIdx.x, tid = threadIdx.x;
  int nbase = b << NPB_SHIFT;
  int nloc = min(NPB, N - nbase);
  cnt[tid] = 0;
  // exclusive scan of bucket counts -> dense bucket bases
  bs[tid] = (tid < nbuck) ? bfill[tid] : 0;
  bs[tid + 256] = (tid + 256 < nbuck) ? bfill[tid + 256] : 0;
  __syncthreads();
  int c0 = bs[2 * tid], c1 = bs[2 * tid + 1];
  int pp = c0 + c1;
  ps[tid] = pp;
  __syncthreads();
  for (int off = 1; off < 256; off <<= 1) {
    int t = (tid >= off) ? ps[tid - off] : 0;
    __syncthreads();
    ps[tid] += t;
    __syncthreads();
  }
  int ep = ps[tid] - pp;               // exclusive over pairs
  bs[2 * tid] = ep;
  bs[2 * tid + 1] = ep + c0;
  __syncthreads();
  int ebeg = bs[b];                    // dense base of this bucket
  int cntB = bfill[b];
  int sbeg = b * BCAP;                 // slab base (read side)
  int send = sbeg + cntB;
  for (int j = sbeg + tid; j < send; j += 256) atomicAdd(&cnt[tmp[j] & (NPB - 1)], 1);
  __syncthreads();
  int v = cnt[tid];
  scan[tid] = v;
  __syncthreads();
  for (int off = 1; off < NPB; off <<= 1) {
    int t = (tid >= off) ? scan[tid - off] : 0;
    __syncthreads();
    scan[tid] += t;
    __syncthreads();
  }
  int myoff = ebeg + scan[tid] - v;    // exclusive, dense
  fillL[tid] = myoff;
  if (tid < nloc) {
    offset[nbase + tid] = myoff;
    dinv[nbase + tid] = rsqrtf((float)(v + 1));   // +1 self-loop
  }
  if (b == nbuck - 1 && tid == NPB - 1) offset[N] = ebeg + scan[tid];   // == E
  __syncthreads();
  // scatter src indices into exact dense CSR slots
  int j = sbeg + tid;
  for (; j + 3 * 256 < send; j += 4 * 256) {
    unsigned p[4];
#pragma unroll
    for (int u = 0; u < 4; ++u) p[u] = tmp[j + u * 256];
#pragma unroll
    for (int u = 0; u < 4; ++u) {
      int pos = atomicAdd(&fillL[p[u] & (NPB - 1)], 1);
      ssrc[pos] = (int)(p[u] >> NPB_SHIFT);
    }
  }
  for (; j < send; j += 256) {
    unsigned p = tmp[j];
    int pos = atomicAdd(&fillL[p & (NPB - 1)], 1);
    ssrc[pos] = (int)(p >> NPB_SHIFT);
  }
}

// ---------------- dense layers: MFMA 16x16x32 f16, output scaled by dinv ------
// Writes g[node] = dinv[node] * (x @ W)[node] as fp16, row stride OS.
template <int K, int COLS, int MT, int KC, int OS, typename XT>
__global__ __launch_bounds__(256) void k_gemm_mfma(const XT* __restrict__ x,
                                                   const float* __restrict__ W,
                                                   const float* __restrict__ dinv,
                                                   _Float16* __restrict__ out, int n) {
  int lane = threadIdx.x & 63;
  int quad = lane >> 4;
  int l15 = lane & 15;
  int gwave = (blockIdx.x * blockDim.x + threadIdx.x) >> 6;
  int nwave = (gridDim.x * blockDim.x) >> 6;
  int ntiles = (n + 15) >> 4;

  half8_t afrag[MT][KC];
#pragma unroll
  for (int m = 0; m < MT; ++m) {
    int colw = m * 16 + l15;
    if (colw > COLS - 1) colw = COLS - 1;
#pragma unroll
    for (int c = 0; c < KC; ++c) {
#pragma unroll
      for (int j = 0; j < 8; ++j) {
        int kk = c * 32 + quad * 8 + j;
        afrag[m][c][j] = (_Float16)W[kk * COLS + colw];
      }
    }
  }

  for (int tile = gwave; tile < ntiles; tile += nwave) {
    int node0 = tile << 4;
    int nodeB = node0 + l15;
    int nodeC = nodeB < n ? nodeB : n - 1;
    const XT* xr = x + (size_t)nodeC * K;
    float dv = dinv[nodeC];
    half8_t bfrag[KC];
#pragma unroll
    for (int c = 0; c < KC; ++c) {
      if constexpr (sizeof(XT) == 4) {
        float4 lo = *(const float4*)(xr + c * 32 + quad * 8);
        float4 hi = *(const float4*)(xr + c * 32 + quad * 8 + 4);
        bfrag[c][0] = (_Float16)lo.x; bfrag[c][1] = (_Float16)lo.y;
        bfrag[c][2] = (_Float16)lo.z; bfrag[c][3] = (_Float16)lo.w;
        bfrag[c][4] = (_Float16)hi.x; bfrag[c][5] = (_Float16)hi.y;
        bfrag[c][6] = (_Float16)hi.z; bfrag[c][7] = (_Float16)hi.w;
      } else {
        bfrag[c] = *(const half8_t*)(xr + c * 32 + quad * 8);
      }
    }
    floatx4 acc[MT];
#pragma unroll
    for (int m = 0; m < MT; ++m) acc[m] = (floatx4){0.f, 0.f, 0.f, 0.f};
#pragma unroll
    for (int c = 0; c < KC; ++c)
#pragma unroll
      for (int m = 0; m < MT; ++m)
        acc[m] = __builtin_amdgcn_mfma_f32_16x16x32_f16(afrag[m][c], bfrag[c], acc[m], 0, 0, 0);

    if (nodeB < n) {
#pragma unroll
      for (int m = 0; m < MT; ++m) {
        int colBase = m * 16 + quad * 4;
        if (colBase < COLS) {
          half4_t hv = {(_Float16)(acc[m][0] * dv), (_Float16)(acc[m][1] * dv),
                        (_Float16)(acc[m][2] * dv), (_Float16)(acc[m][3] * dv)};
          *(half4_t*)(out + (size_t)nodeB * OS + colBase) = hv;
        }
      }
    }
  }
}

// ---------------- aggregation: 4 nodes per wave, 8 gathers in flight ----------
// At the random-128B-line fetch wall (~2.26 TB/s) and the per-XCD unique-line
// byte floor -- do not restructure (measured r0 vs r2: 3x MLP, zero delta).

__device__ __forceinline__ void addacc(half2_t* acc, uint4 r) {
  acc[0] += H2(r.x); acc[1] += H2(r.y); acc[2] += H2(r.z); acc[3] += H2(r.w);
}

template <int F, int S8, bool RELU, bool OUT_HALF>
__global__ __launch_bounds__(256) void k_agg_v4(const uint4* __restrict__ g8,
                                                const int* __restrict__ offset,
                                                const int* __restrict__ ssrc,
                                                const float* __restrict__ dinv,
                                                const float* __restrict__ bias,
                                                void* __restrict__ outp, int n) {
  constexpr int F8 = F / 8;            // used octets per row (8 or 5)
  int lane = threadIdx.x & 63;
  int g = lane >> 3;                   // edge group 0..7
  int t = lane & 7;                    // feature octet
  int wave = (blockIdx.x * blockDim.x + threadIdx.x) >> 6;
  int nb = wave * 4;                   // first node of this wave
  if (nb >= n) return;
  bool tv = t < F8;

  // self-loop gathers first (independent, start early)
  uint4 sv[4];
#pragma unroll
  for (int w = 0; w < 4; ++w) {
    int node = nb + w;
    int nc = node < n ? node : n - 1;
    sv[w] = (tv && g == 0 && node < n) ? g8[(size_t)nc * S8 + t]
                                       : make_uint4(0, 0, 0, 0);
  }

  int jj[4], ee[4];
  float di[4];
#pragma unroll
  for (int w = 0; w < 4; ++w) {
    int node = nb + w;
    bool nv = node < n;
    int nc = nv ? node : n - 1;
    int b0 = offset[nc];
    int b1 = offset[nc + 1];
    jj[w] = b0;
    ee[w] = nv ? b1 : b0;
    di[w] = dinv[nc];
  }

  half2_t acc[4][4];
#pragma unroll
  for (int w = 0; w < 4; ++w) {
#pragma unroll
    for (int k = 0; k < 4; ++k) acc[w][k] = H2(0u);
    addacc(acc[w], sv[w]);
  }

  // main loop: up to 16 edges per node per iteration, 8 gathers in flight
  for (;;) {
    bool a0[4], a1[4];
    bool any = false;
#pragma unroll
    for (int w = 0; w < 4; ++w) {
      a0[w] = jj[w] + 8 <= ee[w];
      a1[w] = jj[w] + 16 <= ee[w];
      any = any || a0[w];
    }
    if (!any) break;
    int s0[4], s1[4];
#pragma unroll
    for (int w = 0; w < 4; ++w) {
      s0[w] = a0[w] ? ssrc[jj[w] + g] : 0;
      s1[w] = a1[w] ? ssrc[jj[w] + 8 + g] : 0;
    }
    uint4 r0[4], r1[4];
#pragma unroll
    for (int w = 0; w < 4; ++w) {
      r0[w] = (a0[w] && tv) ? g8[(size_t)s0[w] * S8 + t] : make_uint4(0, 0, 0, 0);
      r1[w] = (a1[w] && tv) ? g8[(size_t)s1[w] * S8 + t] : make_uint4(0, 0, 0, 0);
    }
#pragma unroll
    for (int w = 0; w < 4; ++w) {
      addacc(acc[w], r0[w]);
      addacc(acc[w], r1[w]);
      jj[w] += a1[w] ? 16 : (a0[w] ? 8 : 0);
    }
  }

  // masked tails (0..7 remaining edges per node), 4 gathers in flight
  {
    int rem[4];
    uint4 rv[4];
#pragma unroll
    for (int w = 0; w < 4; ++w) {
      rem[w] = ee[w] - jj[w];
      int gi = (g < rem[w]) ? g : (rem[w] - 1);
      int sW = rem[w] > 0 ? ssrc[jj[w] + gi] : 0;
      rv[w] = (tv && g < rem[w]) ? g8[(size_t)sW * S8 + t] : make_uint4(0, 0, 0, 0);
    }
#pragma unroll
    for (int w = 0; w < 4; ++w) addacc(acc[w], rv[w]);
  }

  // reduce across the 8 groups (packed shuffles) and write out
#pragma unroll
  for (int w = 0; w < 4; ++w) {
#pragma unroll
    for (int k = 0; k < 4; ++k) {
      int u = __builtin_bit_cast(int, acc[w][k]);
      acc[w][k] += H2((unsigned)__shfl_xor(u, 8));
      u = __builtin_bit_cast(int, acc[w][k]);
      acc[w][k] += H2((unsigned)__shfl_xor(u, 16));
      u = __builtin_bit_cast(int, acc[w][k]);
      acc[w][k] += H2((unsigned)__shfl_xor(u, 32));
    }
    int node = nb + w;
    if (node < n && lane < F8) {
      float f[8];
#pragma unroll
      for (int k = 0; k < 4; ++k) {
        f[2 * k] = (float)acc[w][k][0];
        f[2 * k + 1] = (float)acc[w][k][1];
      }
      const float* bb = bias + lane * 8;
      float o[8];
#pragma unroll
      for (int j = 0; j < 8; ++j) {
        o[j] = fmaf(f[j], di[w], bb[j]);
        if (RELU) o[j] = fmaxf(o[j], 0.f);
      }
      if (OUT_HALF) {
        _Float16* op = (_Float16*)outp + (size_t)node * F + lane * 8;
        half2_t p0 = {(_Float16)o[0], (_Float16)o[1]};
        half2_t p1 = {(_Float16)o[2], (_Float16)o[3]};
        half2_t p2 = {(_Float16)o[4], (_Float16)o[5]};
        half2_t p3 = {(_Float16)o[6], (_Float16)o[7]};
        uint4 wv;
        wv.x = __builtin_bit_cast(unsigned, p0);
        wv.y = __builtin_bit_cast(unsigned, p1);
        wv.z = __builtin_bit_cast(unsigned, p2);
        wv.w = __builtin_bit_cast(unsigned, p3);
        *(uint4*)op = wv;
      } else {
        float* op = (float*)outp + (size_t)node * F + lane * 8;
        *(float4*)op = make_float4(o[0], o[1], o[2], o[3]);
        *(float4*)(op + 4) = make_float4(o[4], o[5], o[6], o[7]);
      }
    }
  }
}

// ---------------- launch ----------------

extern "C" void kernel_launch(void* const* d_in, const int* in_sizes, int n_in,
                              void* d_out, int out_size, void* d_ws, size_t ws_size,
                              hipStream_t stream) {
  const float* x  = (const float*)d_in[0];
  const int*   ei = (const int*)d_in[1];
  const float* W1 = (const float*)d_in[2];
  const float* b1 = (const float*)d_in[3];
  const float* W2 = (const float*)d_in[4];
  const float* b2 = (const float*)d_in[5];
  float* out = (float*)d_out;

  const int F_IN = 128, HID = 64, C = 40;
  int N = in_sizes[0] / F_IN;
  int E = in_sizes[1] / 2;
  const int* src = ei;
  const int* dst = ei + E;
  int nbuck = (N + NPB - 1) >> NPB_SHIFT;   // 391 for N=100000

  char* w = (char*)d_ws;
  size_t o = 0;
  auto alloc = [&](size_t bytes) -> void* {
    void* p = w + o;
    o = (o + bytes + 255) & ~(size_t)255;
    return p;
  };
  float*    dinv   = (float*)alloc((size_t)N * 4);
  int*      offset = (int*)alloc((size_t)(N + 1) * 4);
  int*      bfill  = (int*)alloc(512 * 4);
  unsigned* tmp    = (unsigned*)alloc((size_t)nbuck * BCAP * 4);
  int*      ssrc   = (int*)alloc((size_t)E * 4);
  _Float16* g1     = (_Float16*)alloc((size_t)N * HID * 2);   // dinv*(xW1), stride 64
  _Float16* h1     = (_Float16*)alloc((size_t)N * HID * 2);   // relu layer-1 out, fp16
  _Float16* g2     = (_Float16*)alloc((size_t)N * C * 2);     // dinv*(h1W2), stride 40

  dim3 b256(256);

  // partition into per-bucket slabs (no pre-count/scan kernels needed)
  hipMemsetAsync(bfill, 0, 512 * 4, stream);
  k_partition<<<dim3((E + CHUNK - 1) / CHUNK), b256, 0, stream>>>(src, dst, bfill, tmp, E, nbuck);
  k_csr_build<<<dim3(nbuck), b256, 0, stream>>>(tmp, bfill, dinv, offset, ssrc, N, E, nbuck);

  // layer 1: g1 = dinv * (x @ W1);  h1 = relu(dinv*(g1[self]+sum g1[src]) + b1)
  k_gemm_mfma<128, 64, 4, 4, 64, float><<<dim3(1536), b256, 0, stream>>>(x, W1, dinv, g1, N);
  k_agg_v4<64, 8, true, true><<<dim3((N + 15) / 16), b256, 0, stream>>>(
      (const uint4*)g1, offset, ssrc, dinv, b1, h1, N);

  // layer 2: g2 = dinv * (h1 @ W2); out = dinv*(g2[self]+sum g2[src]) + b2
  k_gemm_mfma<64, 40, 3, 2, 40, _Float16><<<dim3(1536), b256, 0, stream>>>(h1, W2, dinv, g2, N);
  k_agg_v4<40, 5, false, false><<<dim3((N + 15) / 16), b256, 0, stream>>>(
      (const uint4*)g2, offset, ssrc, dinv, b2, out, N);
}